// Round 3
// baseline (127.023 us; speedup 1.0000x reference)
//
#include <hip/hip_runtime.h>

// LengthRegulator: B=32, T=256, D=384, MAX_LEN=2048
// out[b,f,:] = x[b, searchsorted(csum[b], f, 'right'), :] if f < mel_len[b] else 0
// mel_len[b] = csum[b, T-1]
//
// v3b: single fused kernel (v3 + nontemporal-store fix: native ext_vector
// float4, since __builtin_nontemporal_store rejects HIP_vector_type).
// Each block re-computes its batch's duration scan (shfl wave-scan +
// cross-wave LDS, ~300 cyc, hidden by TLP: 8 blocks/CU) and expands FPB=32
// frames. Removes the scan dispatch + graph gap + idx_tbl round-trip.
// XCD-swizzled block ids (4 batches per XCD L2); nontemporal stores for out
// (write-once stream, keep x resident in L2).

#define BB 32
#define TT 256
#define DD 384
#define MAXLEN 2048
#define D4 (DD / 4)            // 96 float4 per frame
#define FPB 32                 // frames per block
#define TILES (MAXLEN / FPB)   // 64 tiles per batch
#define NBLK (BB * TILES)      // 2048 blocks

typedef float vf4 __attribute__((ext_vector_type(4)));

__global__ __launch_bounds__(256) void fused_kernel(const float* __restrict__ x,
                                                    const int* __restrict__ duration,
                                                    float* __restrict__ out,
                                                    float* __restrict__ mel_out) {
    __shared__ int s_csum[TT];
    __shared__ int s_wsum[4];
    __shared__ int s_idx[FPB];

    // XCD-aware swizzle (bijective: NBLK % 8 == 0): consecutive logical ids
    // share an XCD -> each XCD L2 serves 4 batches of x (1.5 MB < 4 MiB).
    const int l = (blockIdx.x & 7) * (NBLK / 8) + (blockIdx.x >> 3);
    const int b = l >> 6;                 // l / TILES
    const int tile = l & (TILES - 1);
    const int tid = threadIdx.x;
    const int lane = tid & 63;
    const int wave = tid >> 6;

    // ---- inclusive scan of duration row (wave shfl + cross-wave LDS) ----
    int v = duration[b * TT + tid];
    #pragma unroll
    for (int off = 1; off < 64; off <<= 1) {
        int n = __shfl_up(v, off, 64);
        if (lane >= off) v += n;
    }
    if (lane == 63) s_wsum[wave] = v;
    __syncthreads();
    int pre = 0;
    #pragma unroll
    for (int w = 0; w < 3; ++w) pre += (w < wave) ? s_wsum[w] : 0;
    const int inc = v + pre;              // csum[b, tid] (inclusive)
    s_csum[tid] = inc;
    if (tile == 0 && tid == TT - 1) {
        // Output buffer is fp32; mel_len written as float value.
        mel_out[b] = (float)inc;
    }
    __syncthreads();

    const int mel = s_csum[TT - 1];

    // ---- frame -> token index for this tile (upper_bound over s_csum) ----
    if (tid < FPB) {
        const int f = tile * FPB + tid;
        int idx = -1;
        if (f < mel) {
            int lo = 0, hi = TT;
            while (lo < hi) {
                int mid = (lo + hi) >> 1;
                if (s_csum[mid] > f) hi = mid; else lo = mid + 1;
            }
            idx = lo;  // f < csum[TT-1] guarantees lo <= TT-1 (clip is a no-op)
        }
        s_idx[tid] = idx;
    }
    __syncthreads();

    vf4* __restrict__ o4 = (vf4*)(out + ((size_t)b * MAXLEN + (size_t)tile * FPB) * DD);

    // idx monotone along frames: first frame invalid -> whole tile invalid.
    if (s_idx[0] < 0) {
        const vf4 z = {0.f, 0.f, 0.f, 0.f};
        #pragma unroll
        for (int i = 0; i < (FPB * D4) / 256; ++i) {
            __builtin_nontemporal_store(z, o4 + i * 256 + tid);
        }
        return;
    }

    const vf4* __restrict__ x4 = (const vf4*)(x + (size_t)b * TT * DD);

    // FPB * D4 = 3072 float4 per tile; 256 threads -> 12 fully-coalesced,
    // fully-unrolled iterations (12 independent loads in flight).
    #pragma unroll
    for (int i = 0; i < (FPB * D4) / 256; ++i) {
        const int g = i * 256 + tid;
        const int fl = g / D4;          // frame within tile (0..31)
        const int vv = g - fl * D4;     // float4 column (0..95)
        const int idx = s_idx[fl];
        vf4 val = {0.f, 0.f, 0.f, 0.f};
        if (idx >= 0) {
            val = x4[(size_t)idx * D4 + vv];
        }
        __builtin_nontemporal_store(val, o4 + g);
    }
}

extern "C" void kernel_launch(void* const* d_in, const int* in_sizes, int n_in,
                              void* d_out, int out_size, void* d_ws, size_t ws_size,
                              hipStream_t stream) {
    const float* x = (const float*)d_in[0];
    const int* duration = (const int*)d_in[1];
    // d_in[2] = max_len (known constant 2048)

    float* out = (float*)d_out;                       // [B, MAXLEN, D] fp32
    float* mel_out = out + (size_t)BB * MAXLEN * DD;  // [B] mel_len, as float values
    (void)d_ws; (void)ws_size;

    fused_kernel<<<NBLK, TT, 0, stream>>>(x, duration, out, mel_out);
}